// Round 1
// baseline (1960.022 us; speedup 1.0000x reference)
//
#include <hip/hip_runtime.h>

typedef __bf16 bf16_t;
typedef __bf16 bf16x8 __attribute__((ext_vector_type(8)));
typedef __bf16 bf16x4 __attribute__((ext_vector_type(4)));
typedef float f32x4 __attribute__((ext_vector_type(4)));

constexpr int NN = 16384;   // nodes
constexpr int F  = 128;     // in/hidden features
constexpr int BM = 64;      // M-tile of big GEMM
constexpr int BK = 64;      // K-tile
constexpr int LDA = 72;     // padded LDS row (bf16 elems): 144 B stride -> 2-way banks (free)
constexpr int LDB = 72;
constexpr int SPLITK = 4;   // K-partitions of the big GEMM -> 1024 blocks = 4 blocks/CU
constexpr int KSPAN  = NN / SPLITK;   // 4096

// ---------------------------------------------------------------------------
// small dense GEMM:  outT[j][i] = sum_k in[i][k] * w[k][j]   (write TRANSPOSED bf16)
// ---------------------------------------------------------------------------
template<bool IN_BF16>
__global__ __launch_bounds__(256)
void small_gemm_T(const void* __restrict__ inp, const float* __restrict__ w,
                  bf16_t* __restrict__ outT)
{
    __shared__ float xt[32 * 132];           // 32 rows x 128 cols, padded
    const int t  = threadIdx.x;
    const int i0 = blockIdx.x * 32;
    {
        const int r = t >> 3, cc = (t & 7) * 16;
        float* dst = &xt[r * 132 + cc];
        if constexpr (!IN_BF16) {
            const float* src = (const float*)inp + (size_t)(i0 + r) * F + cc;
            float4 v0 = ((const float4*)src)[0];
            float4 v1 = ((const float4*)src)[1];
            float4 v2 = ((const float4*)src)[2];
            float4 v3 = ((const float4*)src)[3];
            ((float4*)dst)[0] = v0; ((float4*)dst)[1] = v1;
            ((float4*)dst)[2] = v2; ((float4*)dst)[3] = v3;
        } else {
            const bf16_t* src = (const bf16_t*)inp + (size_t)(i0 + r) * F + cc;
            bf16x8 v0 = ((const bf16x8*)src)[0];
            bf16x8 v1 = ((const bf16x8*)src)[1];
            #pragma unroll
            for (int q = 0; q < 8; q++) { dst[q] = (float)v0[q]; dst[8 + q] = (float)v1[q]; }
        }
    }
    __syncthreads();
    const int j  = t & 127;
    const int r0 = (t >> 7) * 16;
    float acc[16];
    #pragma unroll
    for (int r = 0; r < 16; r++) acc[r] = 0.f;
    for (int k4 = 0; k4 < F / 4; k4++) {
        const float w0 = w[(k4 * 4 + 0) * F + j];
        const float w1v = w[(k4 * 4 + 1) * F + j];
        const float w2v = w[(k4 * 4 + 2) * F + j];
        const float w3v = w[(k4 * 4 + 3) * F + j];
        #pragma unroll
        for (int r = 0; r < 16; r++) {
            const float4 xv = *(const float4*)&xt[(r0 + r) * 132 + k4 * 4];
            acc[r] += xv.x * w0 + xv.y * w1v + xv.z * w2v + xv.w * w3v;
        }
    }
    bf16_t* dst = outT + (size_t)j * NN + i0 + r0;
    #pragma unroll
    for (int r = 0; r < 16; r++) dst[r] = (bf16_t)acc[r];
}

// ---------------------------------------------------------------------------
// big aggregation GEMM with split-K:  Ppart[kq] = Aadj[:, kq-range] @ B[kq-range, :]
//   Aadj fp32 [NN][NN] (bf16-converted during staging; non-temporal loads)
//   BT   bf16 [F][NN]
// grid (NN/BM, SPLITK); block 256 = 4 waves; 4 blocks/CU for latency hiding.
// ---------------------------------------------------------------------------
__global__ __launch_bounds__(256, 4)
void agg_gemm_split(const float* __restrict__ Aadj, const bf16_t* __restrict__ BT,
                    float* __restrict__ Ppart)
{
    __shared__ bf16_t sA[BM * LDA];   //  9.2 KB
    __shared__ bf16_t sB[F * LDB];    // 18.4 KB
    const int t = threadIdx.x;
    const int m0 = blockIdx.x * BM;
    const int kq = blockIdx.y;
    const int kbeg = kq * KSPAN;
    const int kend = kbeg + KSPAN;
    const int w = t >> 6, lane = t & 63, quad = lane >> 4, l16 = lane & 15;

    f32x4 acc[4][2];
    #pragma unroll
    for (int mf = 0; mf < 4; mf++)
        #pragma unroll
        for (int nf = 0; nf < 2; nf++) acc[mf][nf] = (f32x4){0.f, 0.f, 0.f, 0.f};

    // staging assignment: A: thread -> row am (0..63), 16 fp32 at col ac
    const int am = t >> 2, ac = (t & 3) * 16;
    const float* aptr = Aadj + (size_t)(m0 + am) * NN + ac;
    bf16_t* sA_dst = &sA[am * LDA + ac];
    // B: thread -> BT row bn (0..127), 32 bf16 at col bc
    const int bn = t >> 1, bc = (t & 1) * 32;
    const bf16_t* bptr = BT + (size_t)bn * NN + bc;
    bf16_t* sB_dst = &sB[bn * LDB + bc];

    f32x4 av[4];
    bf16x8 bv[4];
    {   // prefetch K-tile 0 into registers (A non-temporal: streaming, no reuse)
        const f32x4* ap = (const f32x4*)(aptr + kbeg);
        av[0] = __builtin_nontemporal_load(ap + 0);
        av[1] = __builtin_nontemporal_load(ap + 1);
        av[2] = __builtin_nontemporal_load(ap + 2);
        av[3] = __builtin_nontemporal_load(ap + 3);
        const bf16x8* bp = (const bf16x8*)(bptr + kbeg);
        bv[0] = bp[0]; bv[1] = bp[1]; bv[2] = bp[2]; bv[3] = bp[3];
    }

    for (int k0 = kbeg; k0 < kend; k0 += BK) {
        // registers -> LDS (fp32 -> bf16 convert for A)
        {
            bf16x8 p0, p1;
            const float* fs = (const float*)av;
            #pragma unroll
            for (int q = 0; q < 8; q++) { p0[q] = (bf16_t)fs[q]; p1[q] = (bf16_t)fs[8 + q]; }
            ((bf16x8*)sA_dst)[0] = p0; ((bf16x8*)sA_dst)[1] = p1;
            ((bf16x8*)sB_dst)[0] = bv[0]; ((bf16x8*)sB_dst)[1] = bv[1];
            ((bf16x8*)sB_dst)[2] = bv[2]; ((bf16x8*)sB_dst)[3] = bv[3];
        }
        __syncthreads();
        // prefetch next K-tile (overlaps MFMA; wraps harmlessly on last iter)
        {
            const int kn = (k0 + BK < kend) ? (k0 + BK) : kbeg;
            const f32x4* ap = (const f32x4*)(aptr + kn);
            av[0] = __builtin_nontemporal_load(ap + 0);
            av[1] = __builtin_nontemporal_load(ap + 1);
            av[2] = __builtin_nontemporal_load(ap + 2);
            av[3] = __builtin_nontemporal_load(ap + 3);
            const bf16x8* bp = (const bf16x8*)(bptr + kn);
            bv[0] = bp[0]; bv[1] = bp[1]; bv[2] = bp[2]; bv[3] = bp[3];
        }
        // compute: 2 k-steps of 32, 4 m-frags x 2 n-frags
        #pragma unroll
        for (int ks = 0; ks < 2; ks++) {
            bf16x8 afr[4], bfr[2];
            #pragma unroll
            for (int mf = 0; mf < 4; mf++)
                afr[mf] = *(const bf16x8*)&sA[(mf * 16 + l16) * LDA + ks * 32 + quad * 8];
            #pragma unroll
            for (int nf = 0; nf < 2; nf++)
                bfr[nf] = *(const bf16x8*)&sB[(w * 32 + nf * 16 + l16) * LDB + ks * 32 + quad * 8];
            #pragma unroll
            for (int mf = 0; mf < 4; mf++)
                #pragma unroll
                for (int nf = 0; nf < 2; nf++)
                    acc[mf][nf] = __builtin_amdgcn_mfma_f32_16x16x32_bf16(
                        afr[mf], bfr[nf], acc[mf][nf], 0, 0, 0);
        }
        __syncthreads();
    }

    // write fp32 partials (no bias/relu here).  C/D layout: row = quad*4+r, col = l16
    float* dst = Ppart + (size_t)kq * NN * F;
    #pragma unroll
    for (int mf = 0; mf < 4; mf++)
        #pragma unroll
        for (int nf = 0; nf < 2; nf++) {
            const int col = w * 32 + nf * 16 + l16;
            #pragma unroll
            for (int r = 0; r < 4; r++) {
                const int row = m0 + mf * 16 + quad * 4 + r;
                dst[(size_t)row * F + col] = acc[mf][nf][r];
            }
        }
}

// ---------------------------------------------------------------------------
// finish layer (non-final): h = relu(sum_kq Ppart[kq] + bias) -> bf16 [NN][F]
// one float4 column-chunk per thread; fully coalesced
// ---------------------------------------------------------------------------
__global__ __launch_bounds__(256)
void finish_h(const float* __restrict__ P, const float* __restrict__ bias,
              bf16_t* __restrict__ h)
{
    const int g = blockIdx.x * 256 + threadIdx.x;     // 0 .. NN*F/4-1
    const int row = g >> 5;                           // F/4 = 32 chunks per row
    const int c4  = g & 31;
    const size_t off = (size_t)row * F + c4 * 4;
    f32x4 s = *(const f32x4*)(P + off);
    #pragma unroll
    for (int kq = 1; kq < SPLITK; kq++)
        s += *(const f32x4*)(P + (size_t)kq * NN * F + off);
    const f32x4 b = *(const f32x4*)(bias + c4 * 4);
    bf16x4 o;
    #pragma unroll
    for (int q = 0; q < 4; q++) {
        float v = s[q] + b[q];
        o[q] = (bf16_t)(v > 0.f ? v : 0.f);
    }
    *(bf16x4*)(h + off) = o;
}

// ---------------------------------------------------------------------------
// finish final: out[i][c] = b3[c] + sum_k relu(sum_kq Ppart[kq][i][k] + b2[k]) * w3[k][c]
// one wave per row (lane l covers cols l and l+64); shuffle-reduce; no LDS
// ---------------------------------------------------------------------------
__global__ __launch_bounds__(256)
void finish_final(const float* __restrict__ P, const float* __restrict__ b2,
                  const float* __restrict__ w3, const float* __restrict__ b3,
                  float* __restrict__ out)
{
    const int t = threadIdx.x, w = t >> 6, l = t & 63;
    const int base = blockIdx.x * 64;
    const float w00 = w3[l * 2],        w01 = w3[l * 2 + 1];
    const float w10 = w3[(l + 64) * 2], w11 = w3[(l + 64) * 2 + 1];
    const float bb0 = b2[l], bb1 = b2[l + 64];
    const float o0 = b3[0], o1 = b3[1];
    for (int rr = 0; rr < 16; rr++) {
        const int row = base + rr * 4 + w;
        const float* p = P + (size_t)row * F;
        float v0 = p[l], v1 = p[l + 64];
        #pragma unroll
        for (int kq = 1; kq < SPLITK; kq++) {
            const float* pk = p + (size_t)kq * NN * F;
            v0 += pk[l]; v1 += pk[l + 64];
        }
        v0 += bb0; v1 += bb1;
        v0 = v0 > 0.f ? v0 : 0.f;
        v1 = v1 > 0.f ? v1 : 0.f;
        float p0 = v0 * w00 + v1 * w10;
        float p1 = v0 * w01 + v1 * w11;
        #pragma unroll
        for (int off = 32; off > 0; off >>= 1) {
            p0 += __shfl_down(p0, off);
            p1 += __shfl_down(p1, off);
        }
        if (l == 0) {
            out[(size_t)row * 2 + 0] = p0 + o0;
            out[(size_t)row * 2 + 1] = p1 + o1;
        }
    }
}

// ---------------------------------------------------------------------------
extern "C" void kernel_launch(void* const* d_in, const int* in_sizes, int n_in,
                              void* d_out, int out_size, void* d_ws, size_t ws_size,
                              hipStream_t stream)
{
    const float* x   = (const float*)d_in[0];
    const float* adj = (const float*)d_in[1];
    const float* w1  = (const float*)d_in[2];
    const float* b1  = (const float*)d_in[3];
    const float* w2  = (const float*)d_in[4];
    const float* b2  = (const float*)d_in[5];
    const float* w3  = (const float*)d_in[6];
    const float* b3  = (const float*)d_in[7];
    float* out = (float*)d_out;

    // workspace: 3 x 4 MB bf16 buffers + 32 MB fp32 split-K partials
    bf16_t* xw1T  = (bf16_t*)d_ws;                    // [F][NN]  (x@w1)^T
    bf16_t* h1    = xw1T + (size_t)F * NN;            // [NN][F]  relu layer-1
    bf16_t* hw2T  = h1   + (size_t)NN * F;            // [F][NN]  (h1@w2)^T
    float*  Ppart = (float*)(hw2T + (size_t)F * NN);  // [SPLITK][NN][F] fp32

    dim3 agrid(NN / BM, SPLITK);

    small_gemm_T<false><<<NN / 32, 256, 0, stream>>>((const void*)x, w1, xw1T);
    agg_gemm_split<<<agrid, 256, 0, stream>>>(adj, xw1T, Ppart);
    finish_h<<<NN * F / 4 / 256, 256, 0, stream>>>(Ppart, b1, h1);
    small_gemm_T<true><<<NN / 32, 256, 0, stream>>>((const void*)h1, w2, hw2T);
    agg_gemm_split<<<agrid, 256, 0, stream>>>(adj, hw2T, Ppart);
    finish_final<<<NN / 64, 256, 0, stream>>>(Ppart, b2, w3, b3, out);
}

// Round 2
// 1851.105 us; speedup vs baseline: 1.0588x; 1.0588x over previous
//
#include <hip/hip_runtime.h>

typedef __bf16 bf16_t;
typedef __bf16 bf16x8 __attribute__((ext_vector_type(8)));
typedef __bf16 bf16x4 __attribute__((ext_vector_type(4)));
typedef float f32x4 __attribute__((ext_vector_type(4)));

constexpr int NN = 16384;   // nodes
constexpr int F  = 128;     // in/hidden features
constexpr int BK = 64;      // K-tile of big GEMM
constexpr int SPLITK = 8;   // K-partitions -> grid 128*8 = 1024 blocks
constexpr int KSPAN  = NN / SPLITK;   // 2048

// ---------------------------------------------------------------------------
// adjacency fp32 -> bf16, pure stream.  16B/lane in, 8B/lane out.
// ---------------------------------------------------------------------------
__global__ __launch_bounds__(256)
void convert_adj(const float* __restrict__ a, bf16_t* __restrict__ o)
{
    const size_t total4 = (size_t)NN * NN / 4;
    const size_t stride = (size_t)gridDim.x * 256;
    for (size_t i = (size_t)blockIdx.x * 256 + threadIdx.x; i < total4; i += stride) {
        f32x4 v = *(const f32x4*)(a + i * 4);
        bf16x4 p;
        #pragma unroll
        for (int q = 0; q < 4; q++) p[q] = (bf16_t)v[q];
        *(bf16x4*)(o + i * 4) = p;
    }
}

// ---------------------------------------------------------------------------
// small dense GEMM:  outT[j][i] = sum_k in[i][k] * w[k][j]   (write TRANSPOSED bf16)
// ---------------------------------------------------------------------------
template<bool IN_BF16>
__global__ __launch_bounds__(256)
void small_gemm_T(const void* __restrict__ inp, const float* __restrict__ w,
                  bf16_t* __restrict__ outT)
{
    __shared__ float xt[32 * 132];           // 32 rows x 128 cols, padded
    const int t  = threadIdx.x;
    const int i0 = blockIdx.x * 32;
    {
        const int r = t >> 3, cc = (t & 7) * 16;
        float* dst = &xt[r * 132 + cc];
        if constexpr (!IN_BF16) {
            const float* src = (const float*)inp + (size_t)(i0 + r) * F + cc;
            float4 v0 = ((const float4*)src)[0];
            float4 v1 = ((const float4*)src)[1];
            float4 v2 = ((const float4*)src)[2];
            float4 v3 = ((const float4*)src)[3];
            ((float4*)dst)[0] = v0; ((float4*)dst)[1] = v1;
            ((float4*)dst)[2] = v2; ((float4*)dst)[3] = v3;
        } else {
            const bf16_t* src = (const bf16_t*)inp + (size_t)(i0 + r) * F + cc;
            bf16x8 v0 = ((const bf16x8*)src)[0];
            bf16x8 v1 = ((const bf16x8*)src)[1];
            #pragma unroll
            for (int q = 0; q < 8; q++) { dst[q] = (float)v0[q]; dst[8 + q] = (float)v1[q]; }
        }
    }
    __syncthreads();
    const int j  = t & 127;
    const int r0 = (t >> 7) * 16;
    float acc[16];
    #pragma unroll
    for (int r = 0; r < 16; r++) acc[r] = 0.f;
    for (int k4 = 0; k4 < F / 4; k4++) {
        const float w0 = w[(k4 * 4 + 0) * F + j];
        const float w1v = w[(k4 * 4 + 1) * F + j];
        const float w2v = w[(k4 * 4 + 2) * F + j];
        const float w3v = w[(k4 * 4 + 3) * F + j];
        #pragma unroll
        for (int r = 0; r < 16; r++) {
            const float4 xv = *(const float4*)&xt[(r0 + r) * 132 + k4 * 4];
            acc[r] += xv.x * w0 + xv.y * w1v + xv.z * w2v + xv.w * w3v;
        }
    }
    bf16_t* dst = outT + (size_t)j * NN + i0 + r0;
    #pragma unroll
    for (int r = 0; r < 16; r++) dst[r] = (bf16_t)acc[r];
}

// ---------------------------------------------------------------------------
// aggregation GEMM, m97/m201 structure:
//   Ppart[kq] = Abf[:, kq-span] @ B[kq-span, :]     (B given as BT bf16 [F][NN])
// 128x128 tile, BK=64, 4 waves (2x2 of 64x64), global_load_lds width-16,
// XOR-swizzled LDS (linear dest + inverse-swizzled SOURCE + swizzled READ),
// bijective XCD swizzle: XCD j owns K-span j -> its 512 KB B-slice is L2-resident.
// ---------------------------------------------------------------------------
__global__ __launch_bounds__(256)
void agg_mm(const bf16_t* __restrict__ Abf, const bf16_t* __restrict__ BT,
            float* __restrict__ Ppart)
{
    __shared__ bf16_t sA[128 * 64];   // [m][k] 16 KB, swizzled
    __shared__ bf16_t sB[128 * 64];   // [n][k] 16 KB, swizzled
    const int t = threadIdx.x;
    const int bid = blockIdx.x;                 // 1024 blocks
    const int swz = (bid & 7) * 128 + (bid >> 3);  // bijective (1024 % 8 == 0)
    const int kq  = swz >> 7;                   // 0..7  (one per XCD)
    const int m0  = (swz & 127) * 128;
    const int kbeg = kq * KSPAN;
    const int w = t >> 6, lane = t & 63;
    const int quad = lane >> 4, l16 = lane & 15;
    const int wr = w >> 1, wc = w & 1;          // wave's 64x64 quadrant

    f32x4 acc[4][4];
    #pragma unroll
    for (int i = 0; i < 4; i++)
        #pragma unroll
        for (int j = 0; j < 4; j++) acc[i][j] = (f32x4){0.f, 0.f, 0.f, 0.f};

    // staging geometry: each gload call = 8 rows x 128 B (one wave, 16 B/lane).
    // stored[row][c8] = logical[row][c8 ^ (row&7)]  (c8 = 16B chunk, 8 per row)
    const int srow8 = lane >> 3;                       // row within 8-row group
    const int sc8   = (lane & 7) ^ srow8;              // logical chunk this lane fetches
    const bf16_t* abase = Abf + (size_t)(m0 + w * 32 + srow8) * NN + sc8 * 8;
    const bf16_t* bbase = BT  + (size_t)(w * 32 + srow8) * NN + sc8 * 8;

    for (int k0 = kbeg; k0 < kbeg + KSPAN; k0 += BK) {
        #pragma unroll
        for (int c = 0; c < 4; c++)
            __builtin_amdgcn_global_load_lds(
                (const unsigned int*)(abase + (size_t)(c * 8) * NN + k0),
                (unsigned int*)&sA[(w * 32 + c * 8) * 64], 16, 0, 0);
        #pragma unroll
        for (int c = 0; c < 4; c++)
            __builtin_amdgcn_global_load_lds(
                (const unsigned int*)(bbase + (size_t)(c * 8) * NN + k0),
                (unsigned int*)&sB[(w * 32 + c * 8) * 64], 16, 0, 0);
        __syncthreads();   // drains vmcnt: tile ready
        #pragma unroll
        for (int ks = 0; ks < 2; ks++) {
            const int cst = (((ks * 4 + quad) ^ (l16 & 7)) * 8);  // swizzled read chunk
            bf16x8 afr[4], bfr[4];
            #pragma unroll
            for (int mf = 0; mf < 4; mf++)
                afr[mf] = *(const bf16x8*)&sA[(wr * 64 + mf * 16 + l16) * 64 + cst];
            #pragma unroll
            for (int nf = 0; nf < 4; nf++)
                bfr[nf] = *(const bf16x8*)&sB[(wc * 64 + nf * 16 + l16) * 64 + cst];
            #pragma unroll
            for (int mf = 0; mf < 4; mf++)
                #pragma unroll
                for (int nf = 0; nf < 4; nf++)
                    acc[mf][nf] = __builtin_amdgcn_mfma_f32_16x16x32_bf16(
                        afr[mf], bfr[nf], acc[mf][nf], 0, 0, 0);
        }
        __syncthreads();
    }

    // C/D layout: row = quad*4 + r, col = l16 (verified)
    float* dst = Ppart + (size_t)kq * NN * F;
    #pragma unroll
    for (int mf = 0; mf < 4; mf++)
        #pragma unroll
        for (int nf = 0; nf < 4; nf++) {
            const int col = wc * 64 + nf * 16 + l16;
            #pragma unroll
            for (int r = 0; r < 4; r++) {
                const int row = m0 + wr * 64 + mf * 16 + quad * 4 + r;
                dst[(size_t)row * F + col] = acc[mf][nf][r];
            }
        }
}

// ---------------------------------------------------------------------------
// finish layer (non-final): h = relu(sum_kq Ppart[kq] + bias) -> bf16 [NN][F]
// ---------------------------------------------------------------------------
__global__ __launch_bounds__(256)
void finish_h(const float* __restrict__ P, const float* __restrict__ bias,
              bf16_t* __restrict__ h)
{
    const int g = blockIdx.x * 256 + threadIdx.x;     // 0 .. NN*F/4-1
    const int row = g >> 5;                           // F/4 = 32 chunks per row
    const int c4  = g & 31;
    const size_t off = (size_t)row * F + c4 * 4;
    f32x4 s = *(const f32x4*)(P + off);
    #pragma unroll
    for (int kq = 1; kq < SPLITK; kq++)
        s += *(const f32x4*)(P + (size_t)kq * NN * F + off);
    const f32x4 b = *(const f32x4*)(bias + c4 * 4);
    bf16x4 o;
    #pragma unroll
    for (int q = 0; q < 4; q++) {
        float v = s[q] + b[q];
        o[q] = (bf16_t)(v > 0.f ? v : 0.f);
    }
    *(bf16x4*)(h + off) = o;
}

// ---------------------------------------------------------------------------
// finish final: out[i][c] = b3[c] + sum_k relu(sum_kq P[kq][i][k] + b2[k]) * w3[k][c]
// ---------------------------------------------------------------------------
__global__ __launch_bounds__(256)
void finish_final(const float* __restrict__ P, const float* __restrict__ b2,
                  const float* __restrict__ w3, const float* __restrict__ b3,
                  float* __restrict__ out)
{
    const int t = threadIdx.x, w = t >> 6, l = t & 63;
    const int base = blockIdx.x * 64;
    const float w00 = w3[l * 2],        w01 = w3[l * 2 + 1];
    const float w10 = w3[(l + 64) * 2], w11 = w3[(l + 64) * 2 + 1];
    const float bb0 = b2[l], bb1 = b2[l + 64];
    const float o0 = b3[0], o1 = b3[1];
    for (int rr = 0; rr < 16; rr++) {
        const int row = base + rr * 4 + w;
        const float* p = P + (size_t)row * F;
        float v0 = p[l], v1 = p[l + 64];
        #pragma unroll
        for (int kq = 1; kq < SPLITK; kq++) {
            const float* pk = p + (size_t)kq * NN * F;
            v0 += pk[l]; v1 += pk[l + 64];
        }
        v0 += bb0; v1 += bb1;
        v0 = v0 > 0.f ? v0 : 0.f;
        v1 = v1 > 0.f ? v1 : 0.f;
        float p0 = v0 * w00 + v1 * w10;
        float p1 = v0 * w01 + v1 * w11;
        #pragma unroll
        for (int off = 32; off > 0; off >>= 1) {
            p0 += __shfl_down(p0, off);
            p1 += __shfl_down(p1, off);
        }
        if (l == 0) {
            out[(size_t)row * 2 + 0] = p0 + o0;
            out[(size_t)row * 2 + 1] = p1 + o1;
        }
    }
}

// ---------------------------------------------------------------------------
extern "C" void kernel_launch(void* const* d_in, const int* in_sizes, int n_in,
                              void* d_out, int out_size, void* d_ws, size_t ws_size,
                              hipStream_t stream)
{
    const float* x   = (const float*)d_in[0];
    const float* adj = (const float*)d_in[1];
    const float* w1  = (const float*)d_in[2];
    const float* b1  = (const float*)d_in[3];
    const float* w2  = (const float*)d_in[4];
    const float* b2  = (const float*)d_in[5];
    const float* w3  = (const float*)d_in[6];
    const float* b3  = (const float*)d_in[7];
    float* out = (float*)d_out;

    // workspace layout (ws >= 4.3 GB):
    bf16_t* Abf  = (bf16_t*)d_ws;                       // [NN][NN] bf16  (512 MB)
    bf16_t* xw1T = Abf  + (size_t)NN * NN;              // [F][NN]  (x@w1)^T   (4 MB)
    bf16_t* h1   = xw1T + (size_t)F * NN;               // [NN][F]  relu layer-1 (4 MB)
    bf16_t* hw2T = h1   + (size_t)NN * F;               // [F][NN]  (h1@w2)^T  (4 MB)
    float*  Ppart = (float*)(hw2T + (size_t)F * NN);    // [SPLITK][NN][F] fp32 (64 MB)

    convert_adj<<<2048, 256, 0, stream>>>(adj, Abf);
    small_gemm_T<false><<<NN / 32, 256, 0, stream>>>((const void*)x, w1, xw1T);
    agg_mm<<<128 * SPLITK, 256, 0, stream>>>(Abf, xw1T, Ppart);
    finish_h<<<NN * F / 4 / 256, 256, 0, stream>>>(Ppart, b1, h1);
    small_gemm_T<true><<<NN / 32, 256, 0, stream>>>((const void*)h1, w2, hw2T);
    agg_mm<<<128 * SPLITK, 256, 0, stream>>>(Abf, hw2T, Ppart);
    finish_final<<<NN / 64, 256, 0, stream>>>(Ppart, b2, w3, b3, out);
}